// Round 2
// baseline (819.272 us; speedup 1.0000x reference)
//
#include <hip/hip_runtime.h>

// (B, S, E, H, WIN) = (16, 4096, 512, 8, 64); attention runs over the batch
// axis (16 tokens) independently per position s. Decomposition:
//   1) qkv = x @ W_in^T + b_in        (65536x512 @ 512x1536)
//   2) per-position 16-token, 8-head, Dh=64 attention
//   3) out = o @ W_out^T + b_out      (65536x512 @ 512x512)
// S is processed in 4 chunks of 1024 to keep ws at 50 MB (compact qkv rows
// mm = b*1024 + sc). Input/output dtype (bf16 vs fp32) is detected on-device.

#define S_LEN  4096
#define CHUNK  1024
#define NCHUNK 4
#define E_DIM  512
#define QKV_LD 1536

typedef __bf16 bf16x8 __attribute__((ext_vector_type(8)));
typedef float  f32x4  __attribute__((ext_vector_type(4)));

__device__ __forceinline__ float b2f(unsigned int u16) {
    return __uint_as_float(u16 << 16);
}
__device__ __forceinline__ unsigned short f2bf(float f) {
    unsigned int u = __float_as_uint(f);
    u += 0x7fffu + ((u >> 16) & 1u);   // RNE
    return (unsigned short)(u >> 16);
}
__device__ __forceinline__ void unpack8(uint4 u, float* f) {
    f[0] = b2f(u.x & 0xffffu); f[1] = b2f(u.x >> 16);
    f[2] = b2f(u.y & 0xffffu); f[3] = b2f(u.y >> 16);
    f[4] = b2f(u.z & 0xffffu); f[5] = b2f(u.z >> 16);
    f[6] = b2f(u.w & 0xffffu); f[7] = b2f(u.w >> 16);
}

// Wave-uniform dtype probe on x[0..63] read as 32-bit words. fp32 N(0,1):
// exponent byte in [90,160] for ~all lanes. Packed bf16 pairs: reconstructed
// exponent byte lands in {0..3} or {234..255} for typical magnitudes.
__device__ __forceinline__ bool detect_f32(const unsigned int* __restrict__ probe) {
    unsigned int w = probe[threadIdx.x & 63];
    unsigned int e = (w >> 23) & 0xffu;
    unsigned long long b = __ballot(e >= 90u && e <= 160u);
    return __popcll(b) >= 32;
}

// Stage 8 elements (16 B of bf16) into LDS from src at element offset off.
template<bool F32>
__device__ __forceinline__ void stage8(unsigned short* lds, const void* src, long off) {
    if (F32) {
        const float* p = (const float*)src + off;
        float4 a = *(const float4*)p;
        float4 c = *(const float4*)(p + 4);
        uint4 u;
        u.x = (unsigned)f2bf(a.x) | ((unsigned)f2bf(a.y) << 16);
        u.y = (unsigned)f2bf(a.z) | ((unsigned)f2bf(a.w) << 16);
        u.z = (unsigned)f2bf(c.x) | ((unsigned)f2bf(c.y) << 16);
        u.w = (unsigned)f2bf(c.z) | ((unsigned)f2bf(c.w) << 16);
        *(uint4*)lds = u;
    } else {
        *(uint4*)lds = *(const uint4*)((const unsigned short*)src + off);
    }
}

// ---------------------------------------------------------------------------
// GEMM C = A @ W^T + bias, fp32 accum, tile 128x128, BK=32, 4 waves,
// mfma_f32_16x16x32_bf16 (A frag: A[m=lane&15][k=(lane>>4)*8+j]; C/D:
// col=lane&15, row=(lane>>4)*4+r — m89/m91-verified).
// MODE 1: A = x (dyn dtype), rows remapped mm->(mm>>10)*S+s0+(mm&1023),
//         C = qkv ws (bf16, compact, ldc=1536).
// MODE 2: A = qkv ws (bf16 always, lda=1536, cols 0..511 = o),
//         C = out (dyn dtype, ldc=512, rows remapped).
// K = 512 in both modes.
// ---------------------------------------------------------------------------
template<int MODE, bool F32>
__device__ void gemm_body(const void* __restrict__ A, const void* __restrict__ W,
                          const void* __restrict__ bias, void* __restrict__ C, int s0)
{
    __shared__ __align__(16) unsigned short As[128 * 32];
    __shared__ __align__(16) unsigned short Bs[128 * 32];

    const int tid  = threadIdx.x;
    const int m0   = blockIdx.x * 128;
    const int n0   = blockIdx.y * 128;
    const int wave = tid >> 6;
    const int lane = tid & 63;
    const int wr   = (wave >> 1) * 64;
    const int wc   = (wave & 1) * 64;
    const int lrow = lane & 15;
    const int lq   = lane >> 4;

    f32x4 acc[4][4];
    #pragma unroll
    for (int i = 0; i < 4; ++i)
        #pragma unroll
        for (int j = 0; j < 4; ++j)
            acc[i][j] = (f32x4){0.f, 0.f, 0.f, 0.f};

    // 512 16B-chunks per operand per K-step; 2 per thread.
    const int r0 = tid >> 2, kc0 = (tid & 3) * 8;
    const int r1 = r0 + 64,  kc1 = kc0;

    long aoff0, aoff1;
    if (MODE == 1) {
        const int mm0 = m0 + r0, mm1 = m0 + r1;
        aoff0 = (long)((mm0 >> 10) * S_LEN + s0 + (mm0 & 1023)) * E_DIM + kc0;
        aoff1 = (long)((mm1 >> 10) * S_LEN + s0 + (mm1 & 1023)) * E_DIM + kc1;
    } else {
        aoff0 = (long)(m0 + r0) * QKV_LD + kc0;
        aoff1 = (long)(m0 + r1) * QKV_LD + kc1;
    }
    const long woff0 = (long)(n0 + r0) * E_DIM + kc0;
    const long woff1 = (long)(n0 + r1) * E_DIM + kc1;

    constexpr bool A_F32 = (MODE == 1) && F32;   // ws A-side is always bf16

    for (int k0 = 0; k0 < E_DIM; k0 += 32) {
        stage8<A_F32>(As + r0 * 32 + kc0, A, aoff0 + k0);
        stage8<A_F32>(As + r1 * 32 + kc1, A, aoff1 + k0);
        stage8<F32>  (Bs + r0 * 32 + kc0, W, woff0 + k0);
        stage8<F32>  (Bs + r1 * 32 + kc1, W, woff1 + k0);
        __syncthreads();

        bf16x8 af[4], bfr[4];
        #pragma unroll
        for (int i = 0; i < 4; ++i) {
            af[i]  = *(const bf16x8*)(As + (wr + i * 16 + lrow) * 32 + lq * 8);
            bfr[i] = *(const bf16x8*)(Bs + (wc + i * 16 + lrow) * 32 + lq * 8);
        }
        #pragma unroll
        for (int mi = 0; mi < 4; ++mi)
            #pragma unroll
            for (int ni = 0; ni < 4; ++ni)
                acc[mi][ni] = __builtin_amdgcn_mfma_f32_16x16x32_bf16(
                    af[mi], bfr[ni], acc[mi][ni], 0, 0, 0);
        __syncthreads();
    }

    #pragma unroll
    for (int mi = 0; mi < 4; ++mi)
        #pragma unroll
        for (int ni = 0; ni < 4; ++ni) {
            const int col = wc + ni * 16 + lrow;
            const float bv = F32 ? ((const float*)bias)[n0 + col]
                                 : b2f(((const unsigned short*)bias)[n0 + col]);
            #pragma unroll
            for (int r = 0; r < 4; ++r) {
                const int row = wr + mi * 16 + lq * 4 + r;
                const float v = acc[mi][ni][r] + bv;
                if (MODE == 1) {
                    ((unsigned short*)C)[(long)(m0 + row) * QKV_LD + n0 + col] = f2bf(v);
                } else {
                    const int mm = m0 + row;
                    const long g = (long)((mm >> 10) * S_LEN + s0 + (mm & 1023)) * E_DIM
                                   + n0 + col;
                    if (F32) ((float*)C)[g] = v;
                    else     ((unsigned short*)C)[g] = f2bf(v);
                }
            }
        }
}

template<int MODE>
__global__ __launch_bounds__(256) void gemm_k(const void* __restrict__ A,
                                              const void* __restrict__ W,
                                              const void* __restrict__ bias,
                                              void* __restrict__ C, int s0,
                                              const unsigned int* __restrict__ probe)
{
    if (detect_f32(probe)) gemm_body<MODE, true>(A, W, bias, C, s0);
    else                   gemm_body<MODE, false>(A, W, bias, C, s0);
}

// ---------------------------------------------------------------------------
// Attention per position sc within chunk: 16 tokens (batch axis), 8 heads,
// Dh=64. qkv compact rows mm = b*CHUNK + sc, stride 1536. One block per sc,
// 128 threads = (h, a). Output o overwrites the q-region of the same rows.
// ---------------------------------------------------------------------------
__global__ __launch_bounds__(128) void attn_kernel(unsigned short* __restrict__ qkv)
{
    __shared__ __align__(16) unsigned short T[16 * 1536];   // 48 KB
    const int tid = threadIdx.x;
    const int sc  = blockIdx.x;

    for (int row = 0; row < 16; ++row) {
        const uint4* src = (const uint4*)(qkv + ((long)row * CHUNK + sc) * QKV_LD);
        uint4* dst = (uint4*)T + row * 192;
        for (int c = tid; c < 192; c += 128) dst[c] = src[c];
    }
    __syncthreads();

    const int h = tid >> 4;
    const int a = tid & 15;

    float q[64];
    {
        const uint4* qp = (const uint4*)(T + a * QKV_LD + h * 64);
        #pragma unroll
        for (int c = 0; c < 8; ++c) {
            float f[8]; unpack8(qp[c], f);
            #pragma unroll
            for (int j = 0; j < 8; ++j) q[c * 8 + j] = f[j];
        }
    }

    float sc_[16];
    #pragma unroll
    for (int b = 0; b < 16; ++b) {
        const uint4* kp = (const uint4*)(T + b * QKV_LD + 512 + h * 64);
        float acc = 0.f;
        #pragma unroll
        for (int c = 0; c < 8; ++c) {
            float f[8]; unpack8(kp[c], f);
            #pragma unroll
            for (int j = 0; j < 8; ++j) acc += q[c * 8 + j] * f[j];
        }
        sc_[b] = acc * 0.125f;   // 1/sqrt(64)
    }

    float mx = sc_[0];
    #pragma unroll
    for (int b = 1; b < 16; ++b) mx = fmaxf(mx, sc_[b]);
    float sum = 0.f;
    #pragma unroll
    for (int b = 0; b < 16; ++b) { sc_[b] = __expf(sc_[b] - mx); sum += sc_[b]; }
    const float inv = 1.f / sum;

    float o[64];
    #pragma unroll
    for (int d = 0; d < 64; ++d) o[d] = 0.f;
    #pragma unroll
    for (int b = 0; b < 16; ++b) {
        const float w = sc_[b] * inv;
        const uint4* vp = (const uint4*)(T + b * QKV_LD + 1024 + h * 64);
        #pragma unroll
        for (int c = 0; c < 8; ++c) {
            float f[8]; unpack8(vp[c], f);
            #pragma unroll
            for (int j = 0; j < 8; ++j) o[c * 8 + j] += w * f[j];
        }
    }

    unsigned short* dst = qkv + ((long)a * CHUNK + sc) * QKV_LD + h * 64;
    #pragma unroll
    for (int c = 0; c < 8; ++c) {
        uint4 u;
        u.x = (unsigned)f2bf(o[c * 8 + 0]) | ((unsigned)f2bf(o[c * 8 + 1]) << 16);
        u.y = (unsigned)f2bf(o[c * 8 + 2]) | ((unsigned)f2bf(o[c * 8 + 3]) << 16);
        u.z = (unsigned)f2bf(o[c * 8 + 4]) | ((unsigned)f2bf(o[c * 8 + 5]) << 16);
        u.w = (unsigned)f2bf(o[c * 8 + 6]) | ((unsigned)f2bf(o[c * 8 + 7]) << 16);
        ((uint4*)dst)[c] = u;
    }
}

extern "C" void kernel_launch(void* const* d_in, const int* in_sizes, int n_in,
                              void* d_out, int out_size, void* d_ws, size_t ws_size,
                              hipStream_t stream)
{
    const void* x     = d_in[0];
    const void* W_in  = d_in[1];
    const void* b_in  = d_in[2];
    const void* W_out = d_in[3];
    const void* b_out = d_in[4];
    const unsigned int* probe = (const unsigned int*)d_in[0];
    unsigned short* qkv = (unsigned short*)d_ws;   // 16*1024 x 1536 bf16 = 50 MB

    for (int c = 0; c < NCHUNK; ++c) {
        const int s0 = c * CHUNK;
        // 1) qkv_chunk = x_chunk @ W_in^T + b_in   (M=16384, N=1536, K=512)
        hipLaunchKernelGGL(gemm_k<1>, dim3(128, 12), dim3(256), 0, stream,
                           x, W_in, b_in, (void*)qkv, s0, probe);
        // 2) per-position attention (o overwrites q-region)
        hipLaunchKernelGGL(attn_kernel, dim3(CHUNK), dim3(128), 0, stream, qkv);
        // 3) out_chunk = o @ W_out^T + b_out       (M=16384, N=512, K=512)
        hipLaunchKernelGGL(gemm_k<2>, dim3(128, 4), dim3(256), 0, stream,
                           (void*)qkv, W_out, b_out, d_out, s0, probe);
    }
}

// Round 3
// 646.644 us; speedup vs baseline: 1.2670x; 1.2670x over previous
//
#include <hip/hip_runtime.h>

// LocalAttention (B,S,E,H,WIN) = (16,4096,512,8,64). Attention runs over the
// batch axis (16 tokens) independently per position s. Decomposition:
//   conv_w : W_in/W_out/b_in/b_out fp32 -> bf16 ws  (once)
//   per S-chunk of 1024:
//     conv_x : x chunk fp32 -> bf16 ws, rows remapped to compact mm=b*1024+sc
//     gemm1  : qkv = xb @ W_in^T + b_in   (16384x1536, K=512, pure bf16, m97)
//     attn   : 16-token / 8-head / Dh=64 attention per position (o -> q-region)
//     gemm2  : out = o @ W_out^T + b_out  (16384x512, K=512; fp32 store remap)
// ws = qkv 50.33 MB + xb 16.78 MB + weights 2.1 MB = 69.2 MB.
// Input dtype measured fp32 (round-2 FETCH/WRITE sizes + passing validation);
// runtime wave-uniform detection retained as a guard on conv + gemm2 store.

#define S_LEN  4096
#define CHUNK  1024
#define NCHUNK 4
#define E_DIM  512
#define QKV_LD 1536

typedef __bf16 bf16x8 __attribute__((ext_vector_type(8)));
typedef float  f32x4  __attribute__((ext_vector_type(4)));

__device__ __forceinline__ float b2f(unsigned int u16) {
    return __uint_as_float(u16 << 16);
}
__device__ __forceinline__ unsigned short f2bf(float f) {
    unsigned int u = __float_as_uint(f);
    u += 0x7fffu + ((u >> 16) & 1u);   // RNE
    return (unsigned short)(u >> 16);
}
__device__ __forceinline__ void unpack8(uint4 u, float* f) {
    f[0] = b2f(u.x & 0xffffu); f[1] = b2f(u.x >> 16);
    f[2] = b2f(u.y & 0xffffu); f[3] = b2f(u.y >> 16);
    f[4] = b2f(u.z & 0xffffu); f[5] = b2f(u.z >> 16);
    f[6] = b2f(u.w & 0xffffu); f[7] = b2f(u.w >> 16);
}
__device__ __forceinline__ uint4 pack8(const float* f) {
    uint4 u;
    u.x = (unsigned)f2bf(f[0]) | ((unsigned)f2bf(f[1]) << 16);
    u.y = (unsigned)f2bf(f[2]) | ((unsigned)f2bf(f[3]) << 16);
    u.z = (unsigned)f2bf(f[4]) | ((unsigned)f2bf(f[5]) << 16);
    u.w = (unsigned)f2bf(f[6]) | ((unsigned)f2bf(f[7]) << 16);
    return u;
}

// Wave-uniform dtype probe on x[0..63] as 32-bit words (fp32 exponent band).
__device__ __forceinline__ bool detect_f32(const unsigned int* __restrict__ probe) {
    unsigned int w = probe[threadIdx.x & 63];
    unsigned int e = (w >> 23) & 0xffu;
    unsigned long long b = __ballot(e >= 90u && e <= 160u);
    return __popcll(b) >= 32;
}

// Async global -> LDS, 16 B per lane. LDS dest = wave-uniform base + lane*16.
__device__ __forceinline__ void gload16(const unsigned short* g, unsigned short* l) {
    __builtin_amdgcn_global_load_lds(
        (const __attribute__((address_space(1))) unsigned int*)g,
        (__attribute__((address_space(3))) unsigned int*)l, 16, 0, 0);
}

// Convert 8 src elements at element-offset off into one bf16 uint4.
template<bool F32>
__device__ __forceinline__ uint4 cvt8(const void* src, long off) {
    if (F32) {
        const float* p = (const float*)src + off;
        float4 a = *(const float4*)p, b = *(const float4*)(p + 4);
        float f[8] = {a.x, a.y, a.z, a.w, b.x, b.y, b.z, b.w};
        return pack8(f);
    }
    return *(const uint4*)((const unsigned short*)src + off);
}

// ---------------------------------------------------------------------------
// Weight/bias conversion (once per launch). dst layout (bf16 elements):
//   [0,786432) W_in | [786432,1048576) W_out | [1048576,1050112) b_in
//   | [1050112,1050624) b_out.  131328 chunks of 8.
// ---------------------------------------------------------------------------
template<bool F32>
__device__ void conv_w_body(const void* Win, const void* Wout, const void* bin,
                            const void* bout, unsigned short* dst)
{
    int c = blockIdx.x * 256 + threadIdx.x;
    if (c >= 131328) return;
    const void* src; long soff; long doff = (long)c * 8;
    if (c < 98304)       { src = Win;  soff = doff; }
    else if (c < 131072) { src = Wout; soff = doff - 786432; }
    else if (c < 131264) { src = bin;  soff = doff - 1048576; }
    else                 { src = bout; soff = doff - 1050112; }
    *(uint4*)(dst + doff) = cvt8<F32>(src, soff);
}
__global__ __launch_bounds__(256) void conv_w_k(const void* Win, const void* Wout,
        const void* bin, const void* bout, unsigned short* dst,
        const unsigned int* __restrict__ probe)
{
    if (detect_f32(probe)) conv_w_body<true>(Win, Wout, bin, bout, dst);
    else                   conv_w_body<false>(Win, Wout, bin, bout, dst);
}

// ---------------------------------------------------------------------------
// x chunk conversion + row remap: xb[mm][0:512] = x[(mm>>10)*S + s0 + (mm&1023)].
// 1,048,576 chunks of 8 elements; 64 chunks per row.
// ---------------------------------------------------------------------------
template<bool F32>
__device__ void conv_x_body(const void* __restrict__ x, unsigned short* __restrict__ xb,
                            int s0)
{
    long c = (long)blockIdx.x * 256 + threadIdx.x;
    const int row = (int)(c >> 6);
    const int col = (int)(c & 63) * 8;
    const long src = ((long)(row >> 10) * S_LEN + s0 + (row & 1023)) * E_DIM + col;
    *(uint4*)(xb + (long)row * E_DIM + col) = cvt8<F32>(x, src);
}
__global__ __launch_bounds__(256) void conv_x_k(const void* __restrict__ x,
        unsigned short* __restrict__ xb, int s0, const unsigned int* __restrict__ probe)
{
    if (detect_f32(probe)) conv_x_body<true>(x, xb, s0);
    else                   conv_x_body<false>(x, xb, s0);
}

// ---------------------------------------------------------------------------
// m97-structure GEMM: C = A @ W^T + bias, all-bf16 operands, fp32 accum.
// Tile 128x128, BK=32, 4 waves x (4x4) mfma_f32_16x16x32_bf16.
// Staging: global_load_lds 16B/lane; wave w stages rows [w*32,w*32+32) of
// each operand (2 ops x 1024 B). A frag: A[m=lane&15][k=(lane>>4)*8+j];
// C/D: col=lane&15, row=(lane>>4)*4+r  [m89/m91-verified].
// MODE 1: A=xb (lda=512), C=qkv bf16 (ldc=1536). MODE 2: A=qkv (lda=1536,
// o in cols 0..511), C=out with row remap, fp32 or bf16 store.
// ---------------------------------------------------------------------------
template<int MODE, bool F32OUT>
__device__ void gemm_body(const unsigned short* __restrict__ A,
                          const unsigned short* __restrict__ W,
                          const unsigned short* __restrict__ bias,
                          void* __restrict__ C, int s0)
{
    __shared__ __align__(16) unsigned short As[128 * 32];
    __shared__ __align__(16) unsigned short Bs[128 * 32];

    const int tid  = threadIdx.x;
    const int m0   = blockIdx.x * 128;
    const int n0   = blockIdx.y * 128;
    const int wave = tid >> 6;
    const int lane = tid & 63;
    const int wr   = (wave >> 1) * 64;
    const int wc   = (wave & 1) * 64;
    const int lrow = lane & 15;
    const int lq   = lane >> 4;
    const int lda  = (MODE == 1) ? E_DIM : QKV_LD;

    f32x4 acc[4][4];
    #pragma unroll
    for (int i = 0; i < 4; ++i)
        #pragma unroll
        for (int j = 0; j < 4; ++j)
            acc[i][j] = (f32x4){0.f, 0.f, 0.f, 0.f};

    // Staging coords: wave w, op t in {0,1}: row = w*32 + t*16 + lane/4,
    // col = (lane&3)*8. LDS dest base (wave-uniform) = w*1024 + t*512 elems.
    const int srow = wave * 32 + (lane >> 2);
    const int scol = (lane & 3) * 8;
    const unsigned short* gA0 = A + (long)(m0 + srow) * lda + scol;
    const unsigned short* gA1 = gA0 + 16 * lda;
    const unsigned short* gB0 = W + (long)(n0 + srow) * E_DIM + scol;
    const unsigned short* gB1 = gB0 + 16 * E_DIM;
    unsigned short* lA = As + wave * 1024;
    unsigned short* lB = Bs + wave * 1024;

    for (int k0 = 0; k0 < E_DIM; k0 += 32) {
        gload16(gA0 + k0, lA);
        gload16(gA1 + k0, lA + 512);
        gload16(gB0 + k0, lB);
        gload16(gB1 + k0, lB + 512);
        __syncthreads();

        bf16x8 af[4], bf[4];
        #pragma unroll
        for (int i = 0; i < 4; ++i) {
            af[i] = *(const bf16x8*)(As + (wr + i * 16 + lrow) * 32 + lq * 8);
            bf[i] = *(const bf16x8*)(Bs + (wc + i * 16 + lrow) * 32 + lq * 8);
        }
        #pragma unroll
        for (int mi = 0; mi < 4; ++mi)
            #pragma unroll
            for (int ni = 0; ni < 4; ++ni)
                acc[mi][ni] = __builtin_amdgcn_mfma_f32_16x16x32_bf16(
                    af[mi], bf[ni], acc[mi][ni], 0, 0, 0);
        __syncthreads();
    }

    #pragma unroll
    for (int mi = 0; mi < 4; ++mi)
        #pragma unroll
        for (int ni = 0; ni < 4; ++ni) {
            const int col = wc + ni * 16 + lrow;
            const float bv = b2f(bias[n0 + col]);
            #pragma unroll
            for (int r = 0; r < 4; ++r) {
                const int row = wr + mi * 16 + lq * 4 + r;
                const float v = acc[mi][ni][r] + bv;
                if (MODE == 1) {
                    ((unsigned short*)C)[(long)(m0 + row) * QKV_LD + n0 + col] = f2bf(v);
                } else {
                    const int mm = m0 + row;
                    const long g = ((long)(mm >> 10) * S_LEN + s0 + (mm & 1023)) * E_DIM
                                   + n0 + col;
                    if (F32OUT) ((float*)C)[g] = v;
                    else        ((unsigned short*)C)[g] = f2bf(v);
                }
            }
        }
}

__global__ __launch_bounds__(256) void gemm1_k(const unsigned short* __restrict__ A,
        const unsigned short* __restrict__ W, const unsigned short* __restrict__ bias,
        unsigned short* __restrict__ C)
{
    gemm_body<1, false>(A, W, bias, C, 0);
}

__global__ __launch_bounds__(256) void gemm2_k(const unsigned short* __restrict__ A,
        const unsigned short* __restrict__ W, const unsigned short* __restrict__ bias,
        void* __restrict__ C, int s0, const unsigned int* __restrict__ probe)
{
    if (detect_f32(probe)) gemm_body<2, true>(A, W, bias, C, s0);
    else                   gemm_body<2, false>(A, W, bias, C, s0);
}

// ---------------------------------------------------------------------------
// Attention per position sc: 16 tokens (batch axis), 8 heads, Dh=64.
// qkv compact rows mm = b*CHUNK + sc, stride 1536. One block per sc,
// 128 threads = (h, a). o overwrites the q-region of the same rows.
// ---------------------------------------------------------------------------
__global__ __launch_bounds__(128) void attn_kernel(unsigned short* __restrict__ qkv)
{
    __shared__ __align__(16) unsigned short T[16 * 1536];   // 48 KB
    const int tid = threadIdx.x;
    const int sc  = blockIdx.x;

    for (int row = 0; row < 16; ++row) {
        const uint4* src = (const uint4*)(qkv + ((long)row * CHUNK + sc) * QKV_LD);
        uint4* dst = (uint4*)T + row * 192;
        for (int c = tid; c < 192; c += 128) dst[c] = src[c];
    }
    __syncthreads();

    const int h = tid >> 4;
    const int a = tid & 15;

    float q[64];
    {
        const uint4* qp = (const uint4*)(T + a * QKV_LD + h * 64);
        #pragma unroll
        for (int c = 0; c < 8; ++c) {
            float f[8]; unpack8(qp[c], f);
            #pragma unroll
            for (int j = 0; j < 8; ++j) q[c * 8 + j] = f[j];
        }
    }

    float sc_[16];
    #pragma unroll
    for (int b = 0; b < 16; ++b) {
        const uint4* kp = (const uint4*)(T + b * QKV_LD + 512 + h * 64);
        float acc = 0.f;
        #pragma unroll
        for (int c = 0; c < 8; ++c) {
            float f[8]; unpack8(kp[c], f);
            #pragma unroll
            for (int j = 0; j < 8; ++j) acc += q[c * 8 + j] * f[j];
        }
        sc_[b] = acc * 0.125f;   // 1/sqrt(64)
    }

    float mx = sc_[0];
    #pragma unroll
    for (int b = 1; b < 16; ++b) mx = fmaxf(mx, sc_[b]);
    float sum = 0.f;
    #pragma unroll
    for (int b = 0; b < 16; ++b) { sc_[b] = __expf(sc_[b] - mx); sum += sc_[b]; }
    const float inv = 1.f / sum;

    float o[64];
    #pragma unroll
    for (int d = 0; d < 64; ++d) o[d] = 0.f;
    #pragma unroll
    for (int b = 0; b < 16; ++b) {
        const float w = sc_[b] * inv;
        const uint4* vp = (const uint4*)(T + b * QKV_LD + 1024 + h * 64);
        #pragma unroll
        for (int c = 0; c < 8; ++c) {
            float f[8]; unpack8(vp[c], f);
            #pragma unroll
            for (int j = 0; j < 8; ++j) o[c * 8 + j] += w * f[j];
        }
    }

    unsigned short* dst = qkv + ((long)a * CHUNK + sc) * QKV_LD + h * 64;
    #pragma unroll
    for (int c = 0; c < 8; ++c)
        ((uint4*)dst)[c] = pack8(o + c * 8);
}

extern "C" void kernel_launch(void* const* d_in, const int* in_sizes, int n_in,
                              void* d_out, int out_size, void* d_ws, size_t ws_size,
                              hipStream_t stream)
{
    const void* x     = d_in[0];
    const void* W_in  = d_in[1];
    const void* b_in  = d_in[2];
    const void* W_out = d_in[3];
    const void* b_out = d_in[4];
    const unsigned int* probe = (const unsigned int*)d_in[0];

    // ws layout (bf16 elements)
    unsigned short* qkv = (unsigned short*)d_ws;            // 25,165,824
    unsigned short* xb  = qkv + 25165824;                   //  8,388,608
    unsigned short* wb  = xb + 8388608;                     //  1,050,624
    const unsigned short* Wi = wb;
    const unsigned short* Wo = wb + 786432;
    const unsigned short* bi = wb + 1048576;
    const unsigned short* bo = wb + 1050112;

    // 0) weights/biases -> bf16 (once)
    hipLaunchKernelGGL(conv_w_k, dim3(514), dim3(256), 0, stream,
                       W_in, W_out, b_in, b_out, wb, probe);

    for (int c = 0; c < NCHUNK; ++c) {
        const int s0 = c * CHUNK;
        // 1) x chunk -> bf16, remapped to compact rows
        hipLaunchKernelGGL(conv_x_k, dim3(4096), dim3(256), 0, stream,
                           x, xb, s0, probe);
        // 2) qkv = xb @ W_in^T + b_in   (M=16384, N=1536, K=512)
        hipLaunchKernelGGL(gemm1_k, dim3(128, 12), dim3(256), 0, stream,
                           xb, Wi, bi, qkv);
        // 3) per-position attention (o overwrites q-region)
        hipLaunchKernelGGL(attn_kernel, dim3(CHUNK), dim3(128), 0, stream, qkv);
        // 4) out = o @ W_out^T + b_out  (M=16384, N=512, K=512)
        hipLaunchKernelGGL(gemm2_k, dim3(128, 4), dim3(256), 0, stream,
                           qkv, Wo, bo, d_out, s0, probe);
    }
}